// Round 1
// baseline (780.702 us; speedup 1.0000x reference)
//
#include <hip/hip_runtime.h>

#define ALP 0.1f          // alpha
#define NINE 0.9f         // 1 - alpha
#define D 64
#define DV 16             // float4 chunks per row

// out = 0.9*h + 0.1*ini_h*bef_X   (elementwise, initializes the accumulator)
__global__ void vsgc_init(const float4* __restrict__ h,
                          const float4* __restrict__ ini_h,
                          const float* __restrict__ bef_X,
                          float4* __restrict__ out, int n4) {
    int i = blockIdx.x * blockDim.x + threadIdx.x;
    if (i >= n4) return;
    int node = i >> 4;                 // DV = 16 float4 per row
    float bx = ALP * bef_X[node];
    float4 hv = h[i];
    float4 iv = ini_h[i];
    float4 o;
    o.x = NINE * hv.x + bx * iv.x;
    o.y = NINE * hv.y + bx * iv.y;
    o.z = NINE * hv.z + bx * iv.z;
    o.w = NINE * hv.w + bx * iv.w;
    out[i] = o;
}

// out[dst] += 0.1 * aft_A[src] * bef_A[dst] * h[src]   (per edge, 16 thr/edge)
__global__ void vsgc_edges(const float4* __restrict__ h,
                           const float* __restrict__ aft_A,
                           const float* __restrict__ bef_A,
                           const int* __restrict__ src,
                           const int* __restrict__ dst,
                           float* __restrict__ out, int E) {
    int tid = blockIdx.x * blockDim.x + threadIdx.x;
    int e = tid >> 4;
    int q = tid & 15;
    if (e >= E) return;
    int s = src[e];
    int d = dst[e];
    float c = ALP * aft_A[s] * bef_A[d];
    float4 hv = h[(size_t)s * DV + q];
    float* op = out + (size_t)d * D + (q << 2);
    unsafeAtomicAdd(op + 0, c * hv.x);
    unsafeAtomicAdd(op + 1, c * hv.y);
    unsafeAtomicAdd(op + 2, c * hv.z);
    unsafeAtomicAdd(op + 3, c * hv.w);
}

extern "C" void kernel_launch(void* const* d_in, const int* in_sizes, int n_in,
                              void* d_out, int out_size, void* d_ws, size_t ws_size,
                              hipStream_t stream) {
    const float* h     = (const float*)d_in[0];
    const float* ini_h = (const float*)d_in[1];
    const float* bef_A = (const float*)d_in[2];
    const float* aft_A = (const float*)d_in[3];
    const float* bef_X = (const float*)d_in[4];
    const int*   src   = (const int*)d_in[5];
    const int*   dst   = (const int*)d_in[6];
    float* out = (float*)d_out;

    const int N = in_sizes[0] / D;      // 100000
    const int E = in_sizes[5];          // 800000
    const int n4 = N * DV;              // float4 count

    {
        int threads = 256;
        int blocks = (n4 + threads - 1) / threads;
        vsgc_init<<<blocks, threads, 0, stream>>>(
            (const float4*)h, (const float4*)ini_h, bef_X, (float4*)out, n4);
    }
    {
        int threads = 256;
        long long total = (long long)E * DV;
        int blocks = (int)((total + threads - 1) / threads);
        vsgc_edges<<<blocks, threads, 0, stream>>>(
            (const float4*)h, aft_A, bef_A, src, dst, out, E);
    }
}

// Round 2
// 232.410 us; speedup vs baseline: 3.3592x; 3.3592x over previous
//
#include <hip/hip_runtime.h>

#define ALP 0.1f          // alpha
#define OMA 0.9f          // 1 - alpha
#define D 64
#define DV 16             // float4 chunks per row
#define SCAN_CHUNK 1024

// ---------------- CSR build ----------------

__global__ void vsgc_hist(const int* __restrict__ dst, int* __restrict__ cnt, int E) {
    int i = blockIdx.x * blockDim.x + threadIdx.x;
    if (i < E) atomicAdd(&cnt[dst[i]], 1);
}

// per-chunk exclusive scan (chunk = 1024), block total -> partial[b]
__global__ void vsgc_scan1(const int* __restrict__ cnt, int* __restrict__ off,
                           int* __restrict__ partial, int N) {
    __shared__ int lds[SCAN_CHUNK];
    int tid = threadIdx.x;
    int i = blockIdx.x * SCAN_CHUNK + tid;
    int v = (i < N) ? cnt[i] : 0;
    lds[tid] = v;
    __syncthreads();
    for (int s = 1; s < SCAN_CHUNK; s <<= 1) {
        int t = (tid >= s) ? lds[tid - s] : 0;
        __syncthreads();
        lds[tid] += t;
        __syncthreads();
    }
    if (i < N) off[i] = lds[tid] - v;            // exclusive
    if (tid == SCAN_CHUNK - 1) partial[blockIdx.x] = lds[tid];
}

__global__ void vsgc_scan2(int* __restrict__ partial, int B) {
    if (blockIdx.x == 0 && threadIdx.x == 0) {
        int s = 0;
        for (int b = 0; b < B; ++b) { int t = partial[b]; partial[b] = s; s += t; }
    }
}

__global__ void vsgc_scan3(int* __restrict__ off, const int* __restrict__ partial, int N) {
    int i = blockIdx.x * blockDim.x + threadIdx.x;
    if (i < N) off[i] += partial[i >> 10];
}

// scatter edge records (src, aft_A[src]) into dst-ordered segments
__global__ void vsgc_fill(const int* __restrict__ src, const int* __restrict__ dst,
                          const float* __restrict__ aft_A,
                          const int* __restrict__ off, int* __restrict__ cur,
                          int2* __restrict__ edges, int E) {
    int i = blockIdx.x * blockDim.x + threadIdx.x;
    if (i >= E) return;
    int s = src[i];
    int d = dst[i];
    int pos = off[d] + atomicAdd(&cur[d], 1);
    edges[pos] = make_int2(s, __float_as_int(aft_A[s]));
}

// ---------------- gather + fused epilogue ----------------
// 16 threads per node, float4 per lane; no atomics, one write per element.
__global__ void vsgc_gather(const float4* __restrict__ h4,
                            const float4* __restrict__ ini4,
                            const float* __restrict__ bef_A,
                            const float* __restrict__ bef_X,
                            const int* __restrict__ off,
                            const int* __restrict__ cnt,
                            const int2* __restrict__ edges,
                            float4* __restrict__ out4, int N) {
    int g = blockIdx.x * (blockDim.x >> 4) + (threadIdx.x >> 4);
    int q = threadIdx.x & 15;
    if (g >= N) return;
    int beg = off[g];
    int n = cnt[g];
    float4 acc = make_float4(0.f, 0.f, 0.f, 0.f);
    for (int i = 0; i < n; ++i) {
        int2 rec = edges[beg + i];
        float w = __int_as_float(rec.y);
        float4 hv = h4[(size_t)rec.x * DV + q];
        acc.x += w * hv.x;
        acc.y += w * hv.y;
        acc.z += w * hv.z;
        acc.w += w * hv.w;
    }
    float cb = ALP * bef_A[g];
    float bx = ALP * bef_X[g];
    float4 hv = h4[(size_t)g * DV + q];
    float4 iv = ini4[(size_t)g * DV + q];
    float4 o;
    o.x = OMA * hv.x + bx * iv.x + cb * acc.x;
    o.y = OMA * hv.y + bx * iv.y + cb * acc.y;
    o.z = OMA * hv.z + bx * iv.z + cb * acc.z;
    o.w = OMA * hv.w + bx * iv.w + cb * acc.w;
    out4[(size_t)g * DV + q] = o;
}

// ---------------- fallback (round-1 atomic version) ----------------

__global__ void vsgc_init(const float4* __restrict__ h,
                          const float4* __restrict__ ini_h,
                          const float* __restrict__ bef_X,
                          float4* __restrict__ out, int n4) {
    int i = blockIdx.x * blockDim.x + threadIdx.x;
    if (i >= n4) return;
    int node = i >> 4;
    float bx = ALP * bef_X[node];
    float4 hv = h[i];
    float4 iv = ini_h[i];
    float4 o;
    o.x = OMA * hv.x + bx * iv.x;
    o.y = OMA * hv.y + bx * iv.y;
    o.z = OMA * hv.z + bx * iv.z;
    o.w = OMA * hv.w + bx * iv.w;
    out[i] = o;
}

__global__ void vsgc_edges_atomic(const float4* __restrict__ h,
                                  const float* __restrict__ aft_A,
                                  const float* __restrict__ bef_A,
                                  const int* __restrict__ src,
                                  const int* __restrict__ dst,
                                  float* __restrict__ out, int E) {
    int tid = blockIdx.x * blockDim.x + threadIdx.x;
    int e = tid >> 4;
    int q = tid & 15;
    if (e >= E) return;
    int s = src[e];
    int d = dst[e];
    float c = ALP * aft_A[s] * bef_A[d];
    float4 hv = h[(size_t)s * DV + q];
    float* op = out + (size_t)d * D + (q << 2);
    unsafeAtomicAdd(op + 0, c * hv.x);
    unsafeAtomicAdd(op + 1, c * hv.y);
    unsafeAtomicAdd(op + 2, c * hv.z);
    unsafeAtomicAdd(op + 3, c * hv.w);
}

extern "C" void kernel_launch(void* const* d_in, const int* in_sizes, int n_in,
                              void* d_out, int out_size, void* d_ws, size_t ws_size,
                              hipStream_t stream) {
    const float* h     = (const float*)d_in[0];
    const float* ini_h = (const float*)d_in[1];
    const float* bef_A = (const float*)d_in[2];
    const float* aft_A = (const float*)d_in[3];
    const float* bef_X = (const float*)d_in[4];
    const int*   src   = (const int*)d_in[5];
    const int*   dst   = (const int*)d_in[6];
    float* out = (float*)d_out;

    const int N = in_sizes[0] / D;      // 100000
    const int E = in_sizes[5];          // 800000

    // workspace layout (ints): cnt[N] | off[N] | cur[N] | partial[SCAN_CHUNK] | edges int2[E]
    size_t intWords = (size_t)3 * N + SCAN_CHUNK;
    size_t intBytes = ((intWords * 4 + 255) / 256) * 256;   // align edges to 256B
    size_t need = intBytes + (size_t)E * sizeof(int2);

    if (ws_size >= need) {
        int* cnt = (int*)d_ws;
        int* off = cnt + N;
        int* cur = off + N;
        int* partial = cur + N;
        int2* edges = (int2*)((char*)d_ws + intBytes);

        // zero cnt/off/cur/partial
        hipMemsetAsync(d_ws, 0, intWords * 4, stream);

        int t = 256;
        vsgc_hist<<<(E + t - 1) / t, t, 0, stream>>>(dst, cnt, E);

        int B = (N + SCAN_CHUNK - 1) / SCAN_CHUNK;
        vsgc_scan1<<<B, SCAN_CHUNK, 0, stream>>>(cnt, off, partial, N);
        vsgc_scan2<<<1, 64, 0, stream>>>(partial, B);
        vsgc_scan3<<<(N + t - 1) / t, t, 0, stream>>>(off, partial, N);

        vsgc_fill<<<(E + t - 1) / t, t, 0, stream>>>(src, dst, aft_A, off, cur, edges, E);

        int nodesPerBlock = t >> 4;  // 16
        vsgc_gather<<<(N + nodesPerBlock - 1) / nodesPerBlock, t, 0, stream>>>(
            (const float4*)h, (const float4*)ini_h, bef_A, bef_X,
            off, cnt, edges, (float4*)out, N);
    } else {
        // fallback: atomic scatter version
        int n4 = N * DV;
        int t = 256;
        vsgc_init<<<(n4 + t - 1) / t, t, 0, stream>>>(
            (const float4*)h, (const float4*)ini_h, bef_X, (float4*)out, n4);
        long long total = (long long)E * DV;
        vsgc_edges_atomic<<<(int)((total + t - 1) / t), t, 0, stream>>>(
            (const float4*)h, aft_A, bef_A, src, dst, out, E);
    }
}